// Round 1
// baseline (1454.169 us; speedup 1.0000x reference)
//
#include <hip/hip_runtime.h>

#define N_NODES 100000
#define N_EDGES 600000
#define DIM 128
#define TILE 32
#define IN_LD 260   // 256 + 4 pad (float) — keeps float4 alignment, breaks bank aliasing
#define H_LD 132    // 128 + 4 pad

__device__ __forceinline__ float mish_f(float v) {
    // mish(x) = x * tanh(softplus(x)); tanh(ln(z)) = (z^2-1)/(z^2+1), z = 1+e^x
    if (v > 30.0f) return v;
    float t = __expf(v);
    float z = 1.0f + t;
    float z2 = z * z;
    return v * (z2 - 1.0f) / (z2 + 1.0f);
}

// Two-layer MLP on a 32-row tile staged in LDS.
// 256 threads, each computes a 4x4 micro-tile of the 32x128 output.
__device__ __forceinline__ void mlp_tile(
    const float* __restrict__ W1, const float* __restrict__ b1,
    const float* __restrict__ W2, const float* __restrict__ b2,
    float (&s_in)[TILE][IN_LD], float (&s_h)[TILE][H_LD],
    float* __restrict__ out_row0)
{
    const int tid = threadIdx.x;
    const int c0 = (tid & 31) << 2;   // output column group (0..124 step 4)
    const int r0 = (tid >> 5) << 2;   // output row group    (0..28  step 4)

    float acc[4][4];
    #pragma unroll
    for (int i = 0; i < 4; ++i)
        #pragma unroll
        for (int j = 0; j < 4; ++j) acc[i][j] = 0.0f;

    // layer 1: [32,256] @ [256,128]
    #pragma unroll 2
    for (int k4 = 0; k4 < (2 * DIM) / 4; ++k4) {
        const float* wr = W1 + (size_t)(4 * k4) * DIM + c0;
        const float4 w0 = *reinterpret_cast<const float4*>(wr);
        const float4 w1 = *reinterpret_cast<const float4*>(wr + DIM);
        const float4 w2 = *reinterpret_cast<const float4*>(wr + 2 * DIM);
        const float4 w3 = *reinterpret_cast<const float4*>(wr + 3 * DIM);
        #pragma unroll
        for (int i = 0; i < 4; ++i) {
            const float4 a = *reinterpret_cast<const float4*>(&s_in[r0 + i][4 * k4]);
            acc[i][0] += a.x * w0.x + a.y * w1.x + a.z * w2.x + a.w * w3.x;
            acc[i][1] += a.x * w0.y + a.y * w1.y + a.z * w2.y + a.w * w3.y;
            acc[i][2] += a.x * w0.z + a.y * w1.z + a.z * w2.z + a.w * w3.z;
            acc[i][3] += a.x * w0.w + a.y * w1.w + a.z * w2.w + a.w * w3.w;
        }
    }

    const float4 bv1 = *reinterpret_cast<const float4*>(b1 + c0);
    #pragma unroll
    for (int i = 0; i < 4; ++i) {
        float4 h;
        h.x = mish_f(acc[i][0] + bv1.x);
        h.y = mish_f(acc[i][1] + bv1.y);
        h.z = mish_f(acc[i][2] + bv1.z);
        h.w = mish_f(acc[i][3] + bv1.w);
        *reinterpret_cast<float4*>(&s_h[r0 + i][c0]) = h;
    }
    __syncthreads();

    float acc2[4][4];
    #pragma unroll
    for (int i = 0; i < 4; ++i)
        #pragma unroll
        for (int j = 0; j < 4; ++j) acc2[i][j] = 0.0f;

    // layer 2: [32,128] @ [128,128]
    #pragma unroll 2
    for (int k4 = 0; k4 < DIM / 4; ++k4) {
        const float* wr = W2 + (size_t)(4 * k4) * DIM + c0;
        const float4 w0 = *reinterpret_cast<const float4*>(wr);
        const float4 w1 = *reinterpret_cast<const float4*>(wr + DIM);
        const float4 w2 = *reinterpret_cast<const float4*>(wr + 2 * DIM);
        const float4 w3 = *reinterpret_cast<const float4*>(wr + 3 * DIM);
        #pragma unroll
        for (int i = 0; i < 4; ++i) {
            const float4 a = *reinterpret_cast<const float4*>(&s_h[r0 + i][4 * k4]);
            acc2[i][0] += a.x * w0.x + a.y * w1.x + a.z * w2.x + a.w * w3.x;
            acc2[i][1] += a.x * w0.y + a.y * w1.y + a.z * w2.y + a.w * w3.y;
            acc2[i][2] += a.x * w0.z + a.y * w1.z + a.z * w2.z + a.w * w3.z;
            acc2[i][3] += a.x * w0.w + a.y * w1.w + a.z * w2.w + a.w * w3.w;
        }
    }

    const float4 bv2 = *reinterpret_cast<const float4*>(b2 + c0);
    #pragma unroll
    for (int i = 0; i < 4; ++i) {
        float4 o;
        o.x = acc2[i][0] + bv2.x;
        o.y = acc2[i][1] + bv2.y;
        o.z = acc2[i][2] + bv2.z;
        o.w = acc2[i][3] + bv2.w;
        *reinterpret_cast<float4*>(out_row0 + (size_t)(r0 + i) * DIM + c0) = o;
    }
}

__global__ __launch_bounds__(256)
void edge_mlp_kernel(const float* __restrict__ x,
                     const float* __restrict__ edge_attr,
                     const int* __restrict__ src_idx,
                     const int* __restrict__ dst_idx,
                     const float* __restrict__ W1, const float* __restrict__ b1,
                     const float* __restrict__ W2, const float* __restrict__ b2,
                     float* __restrict__ e_out, float* __restrict__ agg)
{
    __shared__ float s_in[TILE][IN_LD];
    __shared__ float s_h[TILE][H_LD];
    __shared__ int s_src[TILE];
    __shared__ int s_dst[TILE];

    const int tid = threadIdx.x;
    const int e_base = blockIdx.x * TILE;

    if (tid < TILE) s_src[tid] = src_idx[e_base + tid];
    else if (tid < 2 * TILE) s_dst[tid - TILE] = dst_idx[e_base + (tid - TILE)];
    __syncthreads();

    // stage edge_attr (cols 0..127) + fused scatter-add into agg
    #pragma unroll
    for (int i = 0; i < 4; ++i) {
        const int f = tid + i * 256;
        const int r = f >> 5;
        const int c = (f & 31) << 2;
        const float4 v = *reinterpret_cast<const float4*>(edge_attr + (size_t)(e_base + r) * DIM + c);
        *reinterpret_cast<float4*>(&s_in[r][c]) = v;
        float* ap = agg + (size_t)s_dst[r] * DIM + c;
        atomicAdd(ap + 0, v.x);
        atomicAdd(ap + 1, v.y);
        atomicAdd(ap + 2, v.z);
        atomicAdd(ap + 3, v.w);
    }
    // stage x[src] + x[dst] (cols 128..255)
    #pragma unroll
    for (int i = 0; i < 4; ++i) {
        const int f = tid + i * 256;
        const int r = f >> 5;
        const int c = (f & 31) << 2;
        const float4 vs = *reinterpret_cast<const float4*>(x + (size_t)s_src[r] * DIM + c);
        const float4 vd = *reinterpret_cast<const float4*>(x + (size_t)s_dst[r] * DIM + c);
        float4 v;
        v.x = vs.x + vd.x; v.y = vs.y + vd.y; v.z = vs.z + vd.z; v.w = vs.w + vd.w;
        *reinterpret_cast<float4*>(&s_in[r][DIM + c]) = v;
    }
    __syncthreads();

    mlp_tile(W1, b1, W2, b2, s_in, s_h, e_out + (size_t)e_base * DIM);
}

__global__ __launch_bounds__(256)
void node_mlp_kernel(const float* __restrict__ x,
                     const float* __restrict__ agg,
                     const float* __restrict__ W1, const float* __restrict__ b1,
                     const float* __restrict__ W2, const float* __restrict__ b2,
                     float* __restrict__ x_out)
{
    __shared__ float s_in[TILE][IN_LD];
    __shared__ float s_h[TILE][H_LD];

    const int tid = threadIdx.x;
    const int n_base = blockIdx.x * TILE;

    #pragma unroll
    for (int i = 0; i < 4; ++i) {
        const int f = tid + i * 256;
        const int r = f >> 5;
        const int c = (f & 31) << 2;
        *reinterpret_cast<float4*>(&s_in[r][c]) =
            *reinterpret_cast<const float4*>(x + (size_t)(n_base + r) * DIM + c);
        *reinterpret_cast<float4*>(&s_in[r][DIM + c]) =
            *reinterpret_cast<const float4*>(agg + (size_t)(n_base + r) * DIM + c);
    }
    __syncthreads();

    mlp_tile(W1, b1, W2, b2, s_in, s_h, x_out + (size_t)n_base * DIM);
}

extern "C" void kernel_launch(void* const* d_in, const int* in_sizes, int n_in,
                              void* d_out, int out_size, void* d_ws, size_t ws_size,
                              hipStream_t stream)
{
    const float* x         = (const float*)d_in[0];
    const float* edge_attr = (const float*)d_in[1];
    const int*   ei        = (const int*)d_in[2];   // [2, E] int32: src then dst
    const float* eW1 = (const float*)d_in[3];
    const float* eb1 = (const float*)d_in[4];
    const float* eW2 = (const float*)d_in[5];
    const float* eb2 = (const float*)d_in[6];
    const float* nW1 = (const float*)d_in[7];
    const float* nb1 = (const float*)d_in[8];
    const float* nW2 = (const float*)d_in[9];
    const float* nb2 = (const float*)d_in[10];

    float* out   = (float*)d_out;
    float* x_out = out;                                  // [N, 128] first
    float* e_out = out + (size_t)N_NODES * DIM;          // then [E, 128]
    float* agg   = (float*)d_ws;                         // [N, 128] scratch

    const int* src_idx = ei;
    const int* dst_idx = ei + N_EDGES;

    hipMemsetAsync(agg, 0, (size_t)N_NODES * DIM * sizeof(float), stream);

    edge_mlp_kernel<<<dim3(N_EDGES / TILE), dim3(256), 0, stream>>>(
        x, edge_attr, src_idx, dst_idx, eW1, eb1, eW2, eb2, e_out, agg);

    node_mlp_kernel<<<dim3(N_NODES / TILE), dim3(256), 0, stream>>>(
        x, agg, nW1, nb1, nW2, nb2, x_out);
}